// Round 6
// baseline (506.335 us; speedup 1.0000x reference)
//
#include <hip/hip_runtime.h>
#include <hip/hip_bf16.h>

typedef __bf16 bf16x8 __attribute__((ext_vector_type(8)));
typedef __bf16 bf16x4 __attribute__((ext_vector_type(4)));
typedef float  f32x4  __attribute__((ext_vector_type(4)));

__device__ __forceinline__ void async_cp16(const __bf16* g, __bf16* l) {
    __builtin_amdgcn_global_load_lds(
        (const __attribute__((address_space(1))) void*)g,
        (__attribute__((address_space(3))) void*)l, 16, 0, 0);
}

// ---------------- build x_in(bf16) = [kg_emb[node_id] | ccle_mlp(ccle)[node_id]] ----------------
__global__ __launch_bounds__(256) void build_x_kernel(
    const float* __restrict__ kg_emb, const float* __restrict__ ccle,
    const float* __restrict__ cw1, const float* __restrict__ cb1,
    const float* __restrict__ cw2, const float* __restrict__ cb2,
    const int* __restrict__ node_id, __bf16* __restrict__ x_in, int Nn)
{
    __shared__ float h[2][32];
    int sub = threadIdx.x >> 7;
    int t   = threadIdx.x & 127;
    int i   = blockIdx.x * 2 + sub;
    if (i < Nn && t < 32) {
        int kid = node_id[i];
        float a = 0.f;
        #pragma unroll
        for (int j = 0; j < 4; j++) a += ccle[kid*4 + j] * cw1[j*32 + t];
        a += cb1[t];
        h[sub][t] = a < 0.f ? 0.01f * a : a;
    }
    __syncthreads();
    if (i < Nn) {
        int kid = node_id[i];
        x_in[i*256 + t] = (__bf16)kg_emb[kid*128 + t];
        float a = 0.f;
        #pragma unroll
        for (int j = 0; j < 32; j++) a += h[sub][j] * cw2[j*128 + t];
        a += cb2[t];
        x_in[i*256 + 128 + t] = (__bf16)a;
    }
}

// ---------------- CSR build ----------------
__global__ void hist_kernel(const int* __restrict__ ei, int* __restrict__ deg, int E) {
    int e = blockIdx.x * 256 + threadIdx.x;
    if (e < E) atomicAdd(&deg[ei[E + e]], 1);
}

__global__ __launch_bounds__(1024) void scan_kernel(
    const int* __restrict__ deg, int* __restrict__ row_off, int* __restrict__ cursor, int Nn)
{
    __shared__ int wsum[16];
    __shared__ int carry_s;
    int t = threadIdx.x;
    int lane = t & 63, wid = t >> 6;
    if (t == 0) carry_s = 0;
    __syncthreads();
    for (int base = 0; base < Nn; base += 1024) {
        int idx = base + t;
        int v = (idx < Nn) ? deg[idx] : 0;
        int incl = v;
        #pragma unroll
        for (int off = 1; off < 64; off <<= 1) {
            int x = __shfl_up(incl, off, 64);
            if (lane >= off) incl += x;
        }
        if (lane == 63) wsum[wid] = incl;
        __syncthreads();
        if (wid == 0) {
            int wv = (lane < 16) ? wsum[lane] : 0;
            #pragma unroll
            for (int off = 1; off < 16; off <<= 1) {
                int x = __shfl_up(wv, off, 64);
                if (lane >= off) wv += x;
            }
            if (lane < 16) wsum[lane] = wv;
        }
        __syncthreads();
        int wprefix = (wid > 0) ? wsum[wid - 1] : 0;
        int excl = carry_s + wprefix + incl - v;
        if (idx < Nn) { row_off[idx] = excl; cursor[idx] = excl; }
        __syncthreads();
        if (t == 1023) carry_s += wsum[15];
        __syncthreads();
    }
    if (t == 0) row_off[Nn] = carry_s;
}

__global__ void scatter_kernel(const int* __restrict__ ei, const int* __restrict__ et,
                               int* __restrict__ cursor, int* __restrict__ cidx, int E) {
    int e = blockIdx.x * 256 + threadIdx.x;
    if (e < E) {
        int d = ei[E + e];
        int pos = atomicAdd(&cursor[d], 1);
        cidx[pos] = (et[e] << 20) | ei[e];   // src < 2^20, et < 8
    }
}

// ---------------- all weight transposes in ONE dispatch ----------------
// z in [0,R): w1->w1t ; [R,2R): w2->w2t ; z==2R: sw1->sw1t ; z==2R+1: sw2->sw2t
__global__ __launch_bounds__(256) void transpose_all_kernel(
    const float* __restrict__ w1, const float* __restrict__ w2,
    const float* __restrict__ sw1, const float* __restrict__ sw2,
    __bf16* __restrict__ w1t, __bf16* __restrict__ w2t,
    __bf16* __restrict__ sw1t, __bf16* __restrict__ sw2t, int R)
{
    __shared__ __bf16 tile[64][65];
    int z = blockIdx.z;
    const float* B; __bf16* Bt;
    if (z < R)            { B = w1 + (size_t)z * 65536;        Bt = w1t + (size_t)z * 65536; }
    else if (z < 2 * R)   { B = w2 + (size_t)(z - R) * 65536;  Bt = w2t + (size_t)(z - R) * 65536; }
    else if (z == 2 * R)  { B = sw1;                            Bt = sw1t; }
    else                  { B = sw2;                            Bt = sw2t; }
    int kb = blockIdx.x * 64, nb = blockIdx.y * 64;
    int t = threadIdx.x;
    for (int idx = t; idx < 4096; idx += 256) {
        int rr = idx >> 6, cc = idx & 63;
        tile[rr][cc] = (__bf16)B[(kb + rr) * 256 + nb + cc];
    }
    __syncthreads();
    for (int idx = t; idx < 4096; idx += 256) {
        int rr = idx >> 6, cc = idx & 63;
        Bt[(nb + rr) * 256 + kb + cc] = tile[cc][rr];
    }
}

// ---------------- WQK[r] = [W_r@q | W_r@k] -> wqkT[col=r*8+h][in] bf16 ----------------
__global__ __launch_bounds__(256) void wqk_build_kernel(
    const float* __restrict__ w, const float* __restrict__ q,
    const float* __restrict__ k, __bf16* __restrict__ wqkT)
{
    __shared__ float qs[1024], ks[1024];
    int r = blockIdx.x, t = threadIdx.x;
    for (int i = t; i < 1024; i += 256) { qs[i] = q[i]; ks[i] = k[i]; }
    __syncthreads();
    int inl = t >> 3, g = t & 7;
    const float* wr = w + (size_t)r * 65536;
    for (int ib = 0; ib < 8; ib++) {
        int in = ib * 32 + inl;
        float pq0=0,pq1=0,pq2=0,pq3=0, pk0=0,pk1=0,pk2=0,pk3=0;
        const float* row = wr + in * 256 + g * 32;
        #pragma unroll 8
        for (int oj = 0; oj < 32; oj++) {
            float wv = row[oj];
            int out = g * 32 + oj;
            pq0 += wv * qs[out*4+0]; pq1 += wv * qs[out*4+1];
            pq2 += wv * qs[out*4+2]; pq3 += wv * qs[out*4+3];
            pk0 += wv * ks[out*4+0]; pk1 += wv * ks[out*4+1];
            pk2 += wv * ks[out*4+2]; pk3 += wv * ks[out*4+3];
        }
        #pragma unroll
        for (int d = 4; d >= 1; d >>= 1) {
            pq0 += __shfl_down(pq0, d, 64); pq1 += __shfl_down(pq1, d, 64);
            pq2 += __shfl_down(pq2, d, 64); pq3 += __shfl_down(pq3, d, 64);
            pk0 += __shfl_down(pk0, d, 64); pk1 += __shfl_down(pk1, d, 64);
            pk2 += __shfl_down(pk2, d, 64); pk3 += __shfl_down(pk3, d, 64);
        }
        if (g == 0) {
            wqkT[(r*8+0)*256 + in] = (__bf16)pq0; wqkT[(r*8+1)*256 + in] = (__bf16)pq1;
            wqkT[(r*8+2)*256 + in] = (__bf16)pq2; wqkT[(r*8+3)*256 + in] = (__bf16)pq3;
            wqkT[(r*8+4)*256 + in] = (__bf16)pk0; wqkT[(r*8+5)*256 + in] = (__bf16)pk1;
            wqkT[(r*8+6)*256 + in] = (__bf16)pk2; wqkT[(r*8+7)*256 + in] = (__bf16)pk3;
        }
    }
}

// ---------------- MFMA GEMM: LDS-staged async, double-buffered, XOR-swizzled ----------------
// XOR swizzle: LDS slot c holds global chunk kq = (c&3)^((row>>1)&3) of row c>>2.
// Keeps global_load_lds's lane-linear LDS constraint while making the frag
// ds_read_b128 pattern 2-way max (free) instead of 8-way.
__global__ __launch_bounds__(256, 3) void gemm_lds_kernel(
    const __bf16* __restrict__ A,
    const __bf16* __restrict__ Bt, long bStride,
    __bf16* __restrict__ C, long cStride,
    const float* __restrict__ bias, float slope,
    int M, int R2, int mb)
{
    __shared__ __bf16 sm[2][8192];
    const int id = blockIdx.x;
    const int xcd = id & 7, slot = id >> 3;
    const int g = xcd + 8 * (slot / R2);
    const int member = slot % R2;
    if (g >= mb) return;
    const int m0 = g * 128, n0 = (member & 1) * 128;
    const int z = member >> 1;
    const __bf16* __restrict__ Bb = Bt + (long)z * bStride;

    const int t = threadIdx.x;
    const int wave = t >> 6, lane = t & 63;
    const int wy = (wave >> 1) * 64, wx = (wave & 1) * 64;
    const int lr = lane & 15, lq = lane >> 4;

    // staging source addresses (XOR-swizzled on the global side)
    int c0 = wave * 128 + lane;
    int row0 = c0 >> 2,        kq0 = ((c0 & 3) ^ ((row0 >> 1) & 3));
    int c1 = c0 + 64;
    int row1 = c1 >> 2,        kq1 = ((c1 & 3) ^ ((row1 >> 1) & 3));
    int ar0 = m0 + row0; if (ar0 >= M) ar0 = M - 1;
    int ar1 = m0 + row1; if (ar1 >= M) ar1 = M - 1;
    const long a_g0 = (long)ar0 * 256 + kq0 * 8;
    const long a_g1 = (long)ar1 * 256 + kq1 * 8;
    const long b_g0 = (long)(n0 + row0) * 256 + kq0 * 8;
    const long b_g1 = (long)(n0 + row1) * 256 + kq1 * 8;
    const int lds_w0 = (wave * 128) * 8, lds_w1 = (wave * 128 + 64) * 8;

    // frag read addresses (swizzle-aware, constant across K-loop)
    int a_lds[4], b_lds[4];
    #pragma unroll
    for (int tm = 0; tm < 4; tm++) {
        int row = wy + tm * 16 + lr;
        a_lds[tm] = (row * 4 + (lq ^ ((row >> 1) & 3))) * 8;
    }
    #pragma unroll
    for (int tn = 0; tn < 4; tn++) {
        int row = wx + tn * 16 + lr;
        b_lds[tn] = 4096 + (row * 4 + (lq ^ ((row >> 1) & 3))) * 8;
    }

    f32x4 acc[4][4];
    #pragma unroll
    for (int a_ = 0; a_ < 4; a_++)
        #pragma unroll
        for (int b_ = 0; b_ < 4; b_++) acc[a_][b_] = (f32x4){0.f, 0.f, 0.f, 0.f};

    async_cp16(A  + a_g0, &sm[0][lds_w0]);
    async_cp16(A  + a_g1, &sm[0][lds_w1]);
    async_cp16(Bb + b_g0, &sm[0][4096 + lds_w0]);
    async_cp16(Bb + b_g1, &sm[0][4096 + lds_w1]);

    #pragma unroll
    for (int it = 0; it < 8; it++) {
        const int cur = it & 1;
        __syncthreads();
        if (it < 7) {
            const int k0 = (it + 1) * 32;
            async_cp16(A  + a_g0 + k0, &sm[cur ^ 1][lds_w0]);
            async_cp16(A  + a_g1 + k0, &sm[cur ^ 1][lds_w1]);
            async_cp16(Bb + b_g0 + k0, &sm[cur ^ 1][4096 + lds_w0]);
            async_cp16(Bb + b_g1 + k0, &sm[cur ^ 1][4096 + lds_w1]);
        }
        bf16x8 af[4], bfr[4];
        #pragma unroll
        for (int tm = 0; tm < 4; tm++) af[tm]  = *(const bf16x8*)(&sm[cur][a_lds[tm]]);
        #pragma unroll
        for (int tn = 0; tn < 4; tn++) bfr[tn] = *(const bf16x8*)(&sm[cur][b_lds[tn]]);
        #pragma unroll
        for (int tm = 0; tm < 4; tm++)
            #pragma unroll
            for (int tn = 0; tn < 4; tn++)
                acc[tm][tn] = __builtin_amdgcn_mfma_f32_16x16x32_bf16(af[tm], bfr[tn], acc[tm][tn], 0, 0, 0);
        __syncthreads();
    }

    __bf16* __restrict__ Cb = C + (long)z * cStride;
    #pragma unroll
    for (int tm = 0; tm < 4; tm++) {
        #pragma unroll
        for (int tn = 0; tn < 4; tn++) {
            int col = n0 + wx + tn * 16 + lr;
            float bcol = bias ? bias[col] : 0.f;
            #pragma unroll
            for (int ii = 0; ii < 4; ii++) {
                int rg = m0 + wy + tm * 16 + lq * 4 + ii;
                if (rg < M) {
                    float v = acc[tm][tn][ii] + bcol;
                    v = v < 0.f ? v * slope : v;
                    Cb[(long)rg * 256 + col] = (__bf16)v;
                }
            }
        }
    }
}

// ---------------- skinny MFMA GEMM: s_qk[N][64] fp32 = x[N][256] @ wqkT[64][256]^T ----------------
__global__ __launch_bounds__(256) void sqk_gemm_kernel(
    const __bf16* __restrict__ A, const __bf16* __restrict__ wqkT,
    float* __restrict__ s_qk, int M)
{
    __shared__ __bf16 Asm[2][4096];
    __shared__ __bf16 Bsm[64 * 264];   // padded rows: 264 elems -> conflict-free frag reads
    const int m0 = blockIdx.x * 128;
    const int t = threadIdx.x;
    const int wave = t >> 6, lane = t & 63;
    const int lr = lane & 15, lq = lane >> 4;

    for (int i = t; i < 2048; i += 256) {
        int row = i >> 5, c8 = i & 31;
        *(uint4*)(&Bsm[row * 264 + c8 * 8]) = *(const uint4*)(wqkT + row * 256 + c8 * 8);
    }

    int c0 = wave * 64 + lane;
    int row0 = c0 >> 2, kq0 = ((c0 & 3) ^ ((row0 >> 1) & 3));
    int c1 = c0 + 256;
    int row1 = c1 >> 2, kq1 = ((c1 & 3) ^ ((row1 >> 1) & 3));
    int ar0 = m0 + row0; if (ar0 >= M) ar0 = M - 1;
    int ar1 = m0 + row1; if (ar1 >= M) ar1 = M - 1;
    const long a_g0 = (long)ar0 * 256 + kq0 * 8;
    const long a_g1 = (long)ar1 * 256 + kq1 * 8;
    const int lds0 = c0 * 8, lds1 = c1 * 8;

    int a_lds[2];
    #pragma unroll
    for (int tm = 0; tm < 2; tm++) {
        int row = wave * 32 + tm * 16 + lr;
        a_lds[tm] = (row * 4 + (lq ^ ((row >> 1) & 3))) * 8;
    }

    f32x4 acc[2][4];
    #pragma unroll
    for (int a_ = 0; a_ < 2; a_++)
        #pragma unroll
        for (int b_ = 0; b_ < 4; b_++) acc[a_][b_] = (f32x4){0.f, 0.f, 0.f, 0.f};

    async_cp16(A + a_g0, &Asm[0][lds0]);
    async_cp16(A + a_g1, &Asm[0][lds1]);

    #pragma unroll
    for (int it = 0; it < 8; it++) {
        const int cur = it & 1;
        __syncthreads();
        if (it < 7) {
            const int k0 = (it + 1) * 32;
            async_cp16(A + a_g0 + k0, &Asm[cur ^ 1][lds0]);
            async_cp16(A + a_g1 + k0, &Asm[cur ^ 1][lds1]);
        }
        const int k0 = it * 32;
        bf16x8 af[2], bfr[4];
        #pragma unroll
        for (int tm = 0; tm < 2; tm++) af[tm] = *(const bf16x8*)(&Asm[cur][a_lds[tm]]);
        #pragma unroll
        for (int tn = 0; tn < 4; tn++)
            bfr[tn] = *(const bf16x8*)(&Bsm[(tn * 16 + lr) * 264 + k0 + lq * 8]);
        #pragma unroll
        for (int tm = 0; tm < 2; tm++)
            #pragma unroll
            for (int tn = 0; tn < 4; tn++)
                acc[tm][tn] = __builtin_amdgcn_mfma_f32_16x16x32_bf16(af[tm], bfr[tn], acc[tm][tn], 0, 0, 0);
        __syncthreads();
    }

    #pragma unroll
    for (int tm = 0; tm < 2; tm++) {
        #pragma unroll
        for (int tn = 0; tn < 4; tn++) {
            int col = tn * 16 + lr;
            #pragma unroll
            for (int ii = 0; ii < 4; ii++) {
                int rg = m0 + wave * 32 + tm * 16 + lq * 4 + ii;
                if (rg < M) s_qk[(long)rg * 64 + col] = acc[tm][tn][ii];
            }
        }
    }
}

// ---------------- attention softmax + aggregation, one wave per node ----------------
// s_qk layout: [node][r*8 + h] (h<4: q-part for dst; h>=4: k-part for src).
// Inner gather loop unrolled 8 pairs deep -> 8 independent 512B row loads in flight.
__global__ __launch_bounds__(256) void agg_kernel(
    const __bf16* __restrict__ XW, const float* __restrict__ s_qk,
    const int* __restrict__ row_off, const int* __restrict__ cidx,
    const float* __restrict__ bias, const __bf16* __restrict__ skipb,
    __bf16* __restrict__ outb, float* __restrict__ outf, float slope, int Nn)
{
    int lane = threadIdx.x & 63;
    int i = blockIdx.x * 4 + (threadIdx.x >> 6);
    if (i >= Nn) return;
    int base = row_off[i];
    int deg = row_off[i + 1] - base;

    int half = lane >> 5;
    int l32 = lane & 31;
    int myh = l32 >> 3;
    int d8 = l32 * 8;

    float acc[8];
    #pragma unroll
    for (int u = 0; u < 8; u++) acc[u] = 0.f;
    float ss0 = 0.f, ss1 = 0.f, ss2 = 0.f, ss3 = 0.f;

    for (int c0 = 0; c0 < deg; c0 += 64) {
        int e = c0 + lane;
        float p0 = 0.f, p1 = 0.f, p2 = 0.f, p3 = 0.f;
        int cc = 0;
        if (e < deg) {
            cc = cidx[base + e];
            int src = cc & 0xFFFFF, et = cc >> 20;
            const float* sq = s_qk + (long)i * 64 + et * 8;
            const float* sk = s_qk + (long)src * 64 + et * 8 + 4;
            float l0 = sq[0] + sk[0]; l0 = l0 < 0.f ? 0.2f * l0 : l0;
            float l1 = sq[1] + sk[1]; l1 = l1 < 0.f ? 0.2f * l1 : l1;
            float l2 = sq[2] + sk[2]; l2 = l2 < 0.f ? 0.2f * l2 : l2;
            float l3 = sq[3] + sk[3]; l3 = l3 < 0.f ? 0.2f * l3 : l3;
            p0 = __expf(fminf(l0, 40.f)); p1 = __expf(fminf(l1, 40.f));
            p2 = __expf(fminf(l2, 40.f)); p3 = __expf(fminf(l3, 40.f));
        }
        ss0 += p0; ss1 += p1; ss2 += p2; ss3 += p3;
        int cnt = min(64, deg - c0);
        for (int j0 = 0; j0 < cnt; j0 += 16) {
            #pragma unroll
            for (int u = 0; u < 8; u++) {
                int srcl = j0 + u * 2 + half;   // OOB lanes carry p=0, cc=0 -> harmless
                float q0 = __shfl(p0, srcl, 64);
                float q1 = __shfl(p1, srcl, 64);
                float q2 = __shfl(p2, srcl, 64);
                float q3 = __shfl(p3, srcl, 64);
                int   cj = __shfl(cc, srcl, 64);
                float w = (myh & 2) ? ((myh & 1) ? q3 : q2) : ((myh & 1) ? q1 : q0);
                int src = cj & 0xFFFFF, et = cj >> 20;
                bf16x8 xv = *(const bf16x8*)(XW + ((long)et * Nn + src) * 256 + d8);
                #pragma unroll
                for (int v = 0; v < 8; v++) acc[v] += w * (float)xv[v];
            }
        }
    }
    #pragma unroll
    for (int u = 0; u < 8; u++) acc[u] += __shfl_xor(acc[u], 32, 64);
    #pragma unroll
    for (int off = 32; off >= 1; off >>= 1) {
        ss0 += __shfl_xor(ss0, off, 64);
        ss1 += __shfl_xor(ss1, off, 64);
        ss2 += __shfl_xor(ss2, off, 64);
        ss3 += __shfl_xor(ss3, off, 64);
    }
    float ssh = (myh & 2) ? ((myh & 1) ? ss3 : ss2) : ((myh & 1) ? ss1 : ss0);
    float inv = 1.f / fmaxf(ssh, 1e-16f);

    float vout[8];
    #pragma unroll
    for (int u = 0; u < 8; u++) {
        float v = acc[u] * inv + bias[d8 + u];
        if (skipb) v += (float)skipb[(long)i * 256 + d8 + u];
        vout[u] = v < 0.f ? slope * v : v;
    }
    if (outb) {
        if (half == 0) {
            __bf16 tmp[8];
            #pragma unroll
            for (int u = 0; u < 8; u++) tmp[u] = (__bf16)vout[u];
            *(uint4*)(outb + (long)i * 256 + d8) = *(const uint4*)tmp;
        }
    } else {
        float4 f4;
        if (half == 0) { f4 = make_float4(vout[0], vout[1], vout[2], vout[3]);
                         *(float4*)(outf + (long)i * 256 + d8) = f4; }
        else           { f4 = make_float4(vout[4], vout[5], vout[6], vout[7]);
                         *(float4*)(outf + (long)i * 256 + d8 + 4) = f4; }
    }
}

extern "C" void kernel_launch(void* const* d_in, const int* in_sizes, int n_in,
                              void* d_out, int out_size, void* d_ws, size_t ws_size,
                              hipStream_t stream)
{
    const float* kg_emb  = (const float*)d_in[0];
    const float* ccle    = (const float*)d_in[1];
    const int*   node_id = (const int*)d_in[2];
    const int*   edge_ix = (const int*)d_in[3];
    const int*   edge_ty = (const int*)d_in[4];
    const float* ccle_w1 = (const float*)d_in[5];
    const float* ccle_b1 = (const float*)d_in[6];
    const float* ccle_w2 = (const float*)d_in[7];
    const float* ccle_b2 = (const float*)d_in[8];
    const float* w1      = (const float*)d_in[9];
    const float* q1      = (const float*)d_in[10];
    const float* k1      = (const float*)d_in[11];
    const float* bias1   = (const float*)d_in[12];
    const float* w2      = (const float*)d_in[13];
    const float* q2      = (const float*)d_in[14];
    const float* k2      = (const float*)d_in[15];
    const float* bias2   = (const float*)d_in[16];
    const float* skip_w1 = (const float*)d_in[17];
    const float* skip_b1 = (const float*)d_in[18];
    const float* skip_w2 = (const float*)d_in[19];
    const float* skip_b2 = (const float*)d_in[20];

    const int Nn = in_sizes[2];
    const int E  = in_sizes[4];
    const int R  = in_sizes[9] / (256 * 256);

    char* p = (char*)d_ws;
    auto alloc = [&](size_t bytes) { char* r = p; p += (bytes + 255) & ~(size_t)255; return r; };
    __bf16* x_in  = (__bf16*)alloc((size_t)Nn * 256 * 2);
    __bf16* x1    = (__bf16*)alloc((size_t)Nn * 256 * 2);
    __bf16* sh    = (__bf16*)alloc((size_t)Nn * 256 * 2);
    __bf16* skipb = (__bf16*)alloc((size_t)Nn * 256 * 2);
    __bf16* XW    = (__bf16*)alloc((size_t)R * Nn * 256 * 2);
    float*  s_qk  = (float*)alloc((size_t)Nn * 64 * 4);
    __bf16* wqkT1 = (__bf16*)alloc((size_t)64 * 256 * 2);
    __bf16* wqkT2 = (__bf16*)alloc((size_t)64 * 256 * 2);
    __bf16* w1t   = (__bf16*)alloc((size_t)R * 65536 * 2);
    __bf16* w2t   = (__bf16*)alloc((size_t)R * 65536 * 2);
    __bf16* sw1t  = (__bf16*)alloc((size_t)65536 * 2);
    __bf16* sw2t  = (__bf16*)alloc((size_t)65536 * 2);
    int* deg     = (int*)alloc((size_t)Nn * 4);
    int* row_off = (int*)alloc((size_t)(Nn + 1) * 4);
    int* cursor  = (int*)alloc((size_t)Nn * 4);
    int* cidx    = (int*)alloc((size_t)E * 4);

    const int mb = (Nn + 127) / 128;
    const int eb = (E + 255) / 256;
    const int grp = (mb + 7) / 8;
    const int R2 = 2 * R;
    const int gemmR_blocks = 8 * grp * R2;
    const int gemm1_blocks = 8 * grp * 2;

    (void)hipMemsetAsync(deg, 0, (size_t)Nn * 4, stream);
    build_x_kernel<<<dim3((Nn + 1) / 2), 256, 0, stream>>>(
        kg_emb, ccle, ccle_w1, ccle_b1, ccle_w2, ccle_b2, node_id, x_in, Nn);
    hist_kernel<<<dim3(eb), 256, 0, stream>>>(edge_ix, deg, E);
    scan_kernel<<<dim3(1), 1024, 0, stream>>>(deg, row_off, cursor, Nn);
    scatter_kernel<<<dim3(eb), 256, 0, stream>>>(edge_ix, edge_ty, cursor, cidx, E);
    transpose_all_kernel<<<dim3(4, 4, 2 * R + 2), 256, 0, stream>>>(
        w1, w2, skip_w1, skip_w2, w1t, w2t, sw1t, sw2t, R);
    wqk_build_kernel<<<dim3(R), 256, 0, stream>>>(w1, q1, k1, wqkT1);
    wqk_build_kernel<<<dim3(R), 256, 0, stream>>>(w2, q2, k2, wqkT2);

    // layer 1
    gemm_lds_kernel<<<dim3(gemmR_blocks), 256, 0, stream>>>(
        x_in, w1t, 65536L, XW, (long)Nn * 256, nullptr, 1.0f, Nn, R2, mb);
    sqk_gemm_kernel<<<dim3(mb), 256, 0, stream>>>(x_in, wqkT1, s_qk, Nn);
    agg_kernel<<<dim3((Nn + 3) / 4), 256, 0, stream>>>(
        XW, s_qk, row_off, cidx, bias1, nullptr, x1, nullptr, 0.01f, Nn);

    // skip path
    gemm_lds_kernel<<<dim3(gemm1_blocks), 256, 0, stream>>>(
        x_in, sw1t, 0L, sh, 0L, skip_b1, 0.01f, Nn, 2, mb);
    gemm_lds_kernel<<<dim3(gemm1_blocks), 256, 0, stream>>>(
        sh, sw2t, 0L, skipb, 0L, skip_b2, 1.0f, Nn, 2, mb);

    // layer 2
    gemm_lds_kernel<<<dim3(gemmR_blocks), 256, 0, stream>>>(
        x1, w2t, 65536L, XW, (long)Nn * 256, nullptr, 1.0f, Nn, R2, mb);
    sqk_gemm_kernel<<<dim3(mb), 256, 0, stream>>>(x1, wqkT2, s_qk, Nn);
    agg_kernel<<<dim3((Nn + 3) / 4), 256, 0, stream>>>(
        XW, s_qk, row_off, cidx, bias2, skipb, nullptr, (float*)d_out, 0.01f, Nn);
}

// Round 7
// 403.704 us; speedup vs baseline: 1.2542x; 1.2542x over previous
//
#include <hip/hip_runtime.h>
#include <hip/hip_bf16.h>

typedef __bf16 bf16x8 __attribute__((ext_vector_type(8)));
typedef float  f32x4  __attribute__((ext_vector_type(4)));
typedef float  v2f    __attribute__((ext_vector_type(2)));

__device__ __forceinline__ void async_cp16(const __bf16* g, __bf16* l) {
    __builtin_amdgcn_global_load_lds(
        (const __attribute__((address_space(1))) void*)g,
        (__attribute__((address_space(3))) void*)l, 16, 0, 0);
}

// ---------------- build x_in(bf16) = [kg_emb[node_id] | ccle_mlp(ccle)[node_id]] ----------------
__global__ __launch_bounds__(256) void build_x_kernel(
    const float* __restrict__ kg_emb, const float* __restrict__ ccle,
    const float* __restrict__ cw1, const float* __restrict__ cb1,
    const float* __restrict__ cw2, const float* __restrict__ cb2,
    const int* __restrict__ node_id, __bf16* __restrict__ x_in, int Nn)
{
    __shared__ float h[2][32];
    int sub = threadIdx.x >> 7;
    int t   = threadIdx.x & 127;
    int i   = blockIdx.x * 2 + sub;
    if (i < Nn && t < 32) {
        int kid = node_id[i];
        float a = 0.f;
        #pragma unroll
        for (int j = 0; j < 4; j++) a += ccle[kid*4 + j] * cw1[j*32 + t];
        a += cb1[t];
        h[sub][t] = a < 0.f ? 0.01f * a : a;
    }
    __syncthreads();
    if (i < Nn) {
        int kid = node_id[i];
        x_in[i*256 + t] = (__bf16)kg_emb[kid*128 + t];
        float a = 0.f;
        #pragma unroll
        for (int j = 0; j < 32; j++) a += h[sub][j] * cw2[j*128 + t];
        a += cb2[t];
        x_in[i*256 + 128 + t] = (__bf16)a;
    }
}

// ---------------- CSR build ----------------
__global__ void hist_kernel(const int* __restrict__ ei, int* __restrict__ deg, int E) {
    int e = blockIdx.x * 256 + threadIdx.x;
    if (e < E) atomicAdd(&deg[ei[E + e]], 1);
}

__global__ __launch_bounds__(1024) void scan_kernel(
    const int* __restrict__ deg, int* __restrict__ row_off, int* __restrict__ cursor, int Nn)
{
    __shared__ int wsum[16];
    __shared__ int carry_s;
    int t = threadIdx.x;
    int lane = t & 63, wid = t >> 6;
    if (t == 0) carry_s = 0;
    __syncthreads();
    for (int base = 0; base < Nn; base += 1024) {
        int idx = base + t;
        int v = (idx < Nn) ? deg[idx] : 0;
        int incl = v;
        #pragma unroll
        for (int off = 1; off < 64; off <<= 1) {
            int x = __shfl_up(incl, off, 64);
            if (lane >= off) incl += x;
        }
        if (lane == 63) wsum[wid] = incl;
        __syncthreads();
        if (wid == 0) {
            int wv = (lane < 16) ? wsum[lane] : 0;
            #pragma unroll
            for (int off = 1; off < 16; off <<= 1) {
                int x = __shfl_up(wv, off, 64);
                if (lane >= off) wv += x;
            }
            if (lane < 16) wsum[lane] = wv;
        }
        __syncthreads();
        int wprefix = (wid > 0) ? wsum[wid - 1] : 0;
        int excl = carry_s + wprefix + incl - v;
        if (idx < Nn) { row_off[idx] = excl; cursor[idx] = excl; }
        __syncthreads();
        if (t == 1023) carry_s += wsum[15];
        __syncthreads();
    }
    if (t == 0) row_off[Nn] = carry_s;
}

__global__ void scatter_kernel(const int* __restrict__ ei, const int* __restrict__ et,
                               int* __restrict__ cursor, int* __restrict__ cidx, int E) {
    int e = blockIdx.x * 256 + threadIdx.x;
    if (e < E) {
        int d = ei[E + e];
        int pos = atomicAdd(&cursor[d], 1);
        cidx[pos] = (et[e] << 20) | ei[e];   // src < 2^20, et < 8
    }
}

// ---------------- all weight transposes in ONE dispatch ----------------
__global__ __launch_bounds__(256) void transpose_all_kernel(
    const float* __restrict__ w1, const float* __restrict__ w2,
    const float* __restrict__ sw1, const float* __restrict__ sw2,
    __bf16* __restrict__ w1t, __bf16* __restrict__ w2t,
    __bf16* __restrict__ sw1t, __bf16* __restrict__ sw2t, int R)
{
    __shared__ __bf16 tile[64][65];
    int z = blockIdx.z;
    const float* B; __bf16* Bt;
    if (z < R)            { B = w1 + (size_t)z * 65536;        Bt = w1t + (size_t)z * 65536; }
    else if (z < 2 * R)   { B = w2 + (size_t)(z - R) * 65536;  Bt = w2t + (size_t)(z - R) * 65536; }
    else if (z == 2 * R)  { B = sw1;                            Bt = sw1t; }
    else                  { B = sw2;                            Bt = sw2t; }
    int kb = blockIdx.x * 64, nb = blockIdx.y * 64;
    int t = threadIdx.x;
    for (int idx = t; idx < 4096; idx += 256) {
        int rr = idx >> 6, cc = idx & 63;
        tile[rr][cc] = (__bf16)B[(kb + rr) * 256 + nb + cc];
    }
    __syncthreads();
    for (int idx = t; idx < 4096; idx += 256) {
        int rr = idx >> 6, cc = idx & 63;
        Bt[(nb + rr) * 256 + kb + cc] = tile[cc][rr];
    }
}

// ---------------- WQK for both layers in one dispatch ----------------
__global__ __launch_bounds__(256) void wqk_build_kernel(
    const float* __restrict__ w1, const float* __restrict__ q1, const float* __restrict__ k1,
    const float* __restrict__ w2, const float* __restrict__ q2, const float* __restrict__ k2,
    __bf16* __restrict__ wqkT1, __bf16* __restrict__ wqkT2, int R)
{
    __shared__ float qs[1024], ks[1024];
    int zz = blockIdx.x, t = threadIdx.x;
    int r = zz % R;
    const float* w = (zz < R) ? w1 : w2;
    const float* q = (zz < R) ? q1 : q2;
    const float* k = (zz < R) ? k1 : k2;
    __bf16* wqkT = (zz < R) ? wqkT1 : wqkT2;
    for (int i = t; i < 1024; i += 256) { qs[i] = q[i]; ks[i] = k[i]; }
    __syncthreads();
    int inl = t >> 3, g = t & 7;
    const float* wr = w + (size_t)r * 65536;
    for (int ib = 0; ib < 8; ib++) {
        int in = ib * 32 + inl;
        float pq0=0,pq1=0,pq2=0,pq3=0, pk0=0,pk1=0,pk2=0,pk3=0;
        const float* row = wr + in * 256 + g * 32;
        #pragma unroll 8
        for (int oj = 0; oj < 32; oj++) {
            float wv = row[oj];
            int out = g * 32 + oj;
            pq0 += wv * qs[out*4+0]; pq1 += wv * qs[out*4+1];
            pq2 += wv * qs[out*4+2]; pq3 += wv * qs[out*4+3];
            pk0 += wv * ks[out*4+0]; pk1 += wv * ks[out*4+1];
            pk2 += wv * ks[out*4+2]; pk3 += wv * ks[out*4+3];
        }
        #pragma unroll
        for (int d = 4; d >= 1; d >>= 1) {
            pq0 += __shfl_down(pq0, d, 64); pq1 += __shfl_down(pq1, d, 64);
            pq2 += __shfl_down(pq2, d, 64); pq3 += __shfl_down(pq3, d, 64);
            pk0 += __shfl_down(pk0, d, 64); pk1 += __shfl_down(pk1, d, 64);
            pk2 += __shfl_down(pk2, d, 64); pk3 += __shfl_down(pk3, d, 64);
        }
        if (g == 0) {
            wqkT[(r*8+0)*256 + in] = (__bf16)pq0; wqkT[(r*8+1)*256 + in] = (__bf16)pq1;
            wqkT[(r*8+2)*256 + in] = (__bf16)pq2; wqkT[(r*8+3)*256 + in] = (__bf16)pq3;
            wqkT[(r*8+4)*256 + in] = (__bf16)pk0; wqkT[(r*8+5)*256 + in] = (__bf16)pk1;
            wqkT[(r*8+6)*256 + in] = (__bf16)pk2; wqkT[(r*8+7)*256 + in] = (__bf16)pk3;
        }
    }
}

// ---------------- batched MFMA GEMM: R-relation XW (fp8 out) + fused skip member ----------------
// Members 0..R2-1: XW[z] = A@Bt[z] (fp8 e4m3 out, no bias). Members R2,R2+1: skip GEMM
// Cskip = lrelu(Askip@Bskip + biasSkip) (bf16 out). XCD swizzle keeps same-A-tile
// members on one XCD (R3-proven FETCH collapse).
__global__ __launch_bounds__(256, 3) void gemm_lds_kernel(
    const __bf16* __restrict__ A, const __bf16* __restrict__ Askip,
    const __bf16* __restrict__ Bt, long bStride, const __bf16* __restrict__ Bskip,
    unsigned char* __restrict__ C8, long cStride,
    __bf16* __restrict__ Cskip, const float* __restrict__ biasSkip, float slopeSkip,
    int M, int R2, int mb)
{
    __shared__ __bf16 sm[2][8192];
    const int R2m = R2 + 2;
    const int id = blockIdx.x;
    const int xcd = id & 7, slot = id >> 3;
    const int g = xcd + 8 * (slot / R2m);
    const int member = slot % R2m;
    if (g >= mb) return;
    const bool isSkip = member >= R2;
    const int m0 = g * 128;
    const int n0 = isSkip ? (member - R2) * 128 : (member & 1) * 128;
    const int z = isSkip ? 0 : (member >> 1);
    const __bf16* __restrict__ Ab = isSkip ? Askip : A;
    const __bf16* __restrict__ Bb = isSkip ? Bskip : (Bt + (long)z * bStride);

    const int t = threadIdx.x;
    const int wave = t >> 6, lane = t & 63;
    const int wy = (wave >> 1) * 64, wx = (wave & 1) * 64;
    const int lr = lane & 15, lq = lane >> 4;

    int c0 = wave * 128 + lane;
    int row0 = c0 >> 2, kq0 = ((c0 & 3) ^ ((row0 >> 1) & 3));
    int c1 = c0 + 64;
    int row1 = c1 >> 2, kq1 = ((c1 & 3) ^ ((row1 >> 1) & 3));
    int ar0 = m0 + row0; if (ar0 >= M) ar0 = M - 1;
    int ar1 = m0 + row1; if (ar1 >= M) ar1 = M - 1;
    const long a_g0 = (long)ar0 * 256 + kq0 * 8;
    const long a_g1 = (long)ar1 * 256 + kq1 * 8;
    const long b_g0 = (long)(n0 + row0) * 256 + kq0 * 8;
    const long b_g1 = (long)(n0 + row1) * 256 + kq1 * 8;
    const int lds_w0 = (wave * 128) * 8, lds_w1 = (wave * 128 + 64) * 8;

    int a_lds[4], b_lds[4];
    #pragma unroll
    for (int tm = 0; tm < 4; tm++) {
        int row = wy + tm * 16 + lr;
        a_lds[tm] = (row * 4 + (lq ^ ((row >> 1) & 3))) * 8;
    }
    #pragma unroll
    for (int tn = 0; tn < 4; tn++) {
        int row = wx + tn * 16 + lr;
        b_lds[tn] = 4096 + (row * 4 + (lq ^ ((row >> 1) & 3))) * 8;
    }

    f32x4 acc[4][4];
    #pragma unroll
    for (int a_ = 0; a_ < 4; a_++)
        #pragma unroll
        for (int b_ = 0; b_ < 4; b_++) acc[a_][b_] = (f32x4){0.f, 0.f, 0.f, 0.f};

    async_cp16(Ab + a_g0, &sm[0][lds_w0]);
    async_cp16(Ab + a_g1, &sm[0][lds_w1]);
    async_cp16(Bb + b_g0, &sm[0][4096 + lds_w0]);
    async_cp16(Bb + b_g1, &sm[0][4096 + lds_w1]);

    #pragma unroll
    for (int it = 0; it < 8; it++) {
        const int cur = it & 1;
        __syncthreads();
        if (it < 7) {
            const int k0 = (it + 1) * 32;
            async_cp16(Ab + a_g0 + k0, &sm[cur ^ 1][lds_w0]);
            async_cp16(Ab + a_g1 + k0, &sm[cur ^ 1][lds_w1]);
            async_cp16(Bb + b_g0 + k0, &sm[cur ^ 1][4096 + lds_w0]);
            async_cp16(Bb + b_g1 + k0, &sm[cur ^ 1][4096 + lds_w1]);
        }
        bf16x8 af[4], bfr[4];
        #pragma unroll
        for (int tm = 0; tm < 4; tm++) af[tm]  = *(const bf16x8*)(&sm[cur][a_lds[tm]]);
        #pragma unroll
        for (int tn = 0; tn < 4; tn++) bfr[tn] = *(const bf16x8*)(&sm[cur][b_lds[tn]]);
        #pragma unroll
        for (int tm = 0; tm < 4; tm++)
            #pragma unroll
            for (int tn = 0; tn < 4; tn++)
                acc[tm][tn] = __builtin_amdgcn_mfma_f32_16x16x32_bf16(af[tm], bfr[tn], acc[tm][tn], 0, 0, 0);
        __syncthreads();
    }

    if (isSkip) {
        #pragma unroll
        for (int tm = 0; tm < 4; tm++) {
            #pragma unroll
            for (int tn = 0; tn < 4; tn++) {
                int col = n0 + wx + tn * 16 + lr;
                float bcol = biasSkip[col];
                #pragma unroll
                for (int ii = 0; ii < 4; ii++) {
                    int rg = m0 + wy + tm * 16 + lq * 4 + ii;
                    if (rg < M) {
                        float v = acc[tm][tn][ii] + bcol;
                        v = v < 0.f ? v * slopeSkip : v;
                        Cskip[(long)rg * 256 + col] = (__bf16)v;
                    }
                }
            }
        }
    } else {
        unsigned char* __restrict__ Cb = C8 + (long)z * cStride;
        #pragma unroll
        for (int tm = 0; tm < 4; tm++) {
            #pragma unroll
            for (int tn = 0; tn < 4; tn++) {
                int col = n0 + wx + tn * 16 + lr;
                #pragma unroll
                for (int ii = 0; ii < 4; ii++) {
                    int rg = m0 + wy + tm * 16 + lq * 4 + ii;
                    if (rg < M) {
                        float v = acc[tm][tn][ii];
                        int pk = __builtin_amdgcn_cvt_pk_fp8_f32(v, v, 0, false);
                        Cb[(long)rg * 256 + col] = (unsigned char)(pk & 0xFF);
                    }
                }
            }
        }
    }
}

// ---------------- skinny MFMA GEMM: s_qk[N][64] fp32 = x[N][256] @ wqkT[64][256]^T ----------------
__global__ __launch_bounds__(256) void sqk_gemm_kernel(
    const __bf16* __restrict__ A, const __bf16* __restrict__ wqkT,
    float* __restrict__ s_qk, int M)
{
    __shared__ __bf16 Asm[2][4096];
    __shared__ __bf16 Bsm[64 * 264];
    const int m0 = blockIdx.x * 128;
    const int t = threadIdx.x;
    const int wave = t >> 6, lane = t & 63;
    const int lr = lane & 15, lq = lane >> 4;

    for (int i = t; i < 2048; i += 256) {
        int row = i >> 5, c8 = i & 31;
        *(uint4*)(&Bsm[row * 264 + c8 * 8]) = *(const uint4*)(wqkT + row * 256 + c8 * 8);
    }

    int c0 = wave * 64 + lane;
    int row0 = c0 >> 2, kq0 = ((c0 & 3) ^ ((row0 >> 1) & 3));
    int c1 = c0 + 256;
    int row1 = c1 >> 2, kq1 = ((c1 & 3) ^ ((row1 >> 1) & 3));
    int ar0 = m0 + row0; if (ar0 >= M) ar0 = M - 1;
    int ar1 = m0 + row1; if (ar1 >= M) ar1 = M - 1;
    const long a_g0 = (long)ar0 * 256 + kq0 * 8;
    const long a_g1 = (long)ar1 * 256 + kq1 * 8;
    const int lds0 = c0 * 8, lds1 = c1 * 8;

    int a_lds[2];
    #pragma unroll
    for (int tm = 0; tm < 2; tm++) {
        int row = wave * 32 + tm * 16 + lr;
        a_lds[tm] = (row * 4 + (lq ^ ((row >> 1) & 3))) * 8;
    }

    f32x4 acc[2][4];
    #pragma unroll
    for (int a_ = 0; a_ < 2; a_++)
        #pragma unroll
        for (int b_ = 0; b_ < 4; b_++) acc[a_][b_] = (f32x4){0.f, 0.f, 0.f, 0.f};

    async_cp16(A + a_g0, &Asm[0][lds0]);
    async_cp16(A + a_g1, &Asm[0][lds1]);

    #pragma unroll
    for (int it = 0; it < 8; it++) {
        const int cur = it & 1;
        __syncthreads();
        if (it < 7) {
            const int k0 = (it + 1) * 32;
            async_cp16(A + a_g0 + k0, &Asm[cur ^ 1][lds0]);
            async_cp16(A + a_g1 + k0, &Asm[cur ^ 1][lds1]);
        }
        const int k0 = it * 32;
        bf16x8 af[2], bfr[4];
        #pragma unroll
        for (int tm = 0; tm < 2; tm++) af[tm] = *(const bf16x8*)(&Asm[cur][a_lds[tm]]);
        #pragma unroll
        for (int tn = 0; tn < 4; tn++)
            bfr[tn] = *(const bf16x8*)(&Bsm[(tn * 16 + lr) * 264 + k0 + lq * 8]);
        #pragma unroll
        for (int tm = 0; tm < 2; tm++)
            #pragma unroll
            for (int tn = 0; tn < 4; tn++)
                acc[tm][tn] = __builtin_amdgcn_mfma_f32_16x16x32_bf16(af[tm], bfr[tn], acc[tm][tn], 0, 0, 0);
        __syncthreads();
    }

    #pragma unroll
    for (int tm = 0; tm < 2; tm++) {
        #pragma unroll
        for (int tn = 0; tn < 4; tn++) {
            int col = tn * 16 + lr;
            #pragma unroll
            for (int ii = 0; ii < 4; ii++) {
                int rg = m0 + wave * 32 + tm * 16 + lq * 4 + ii;
                if (rg < M) s_qk[(long)rg * 64 + col] = acc[tm][tn][ii];
            }
        }
    }
}

// ---------------- attention softmax + aggregation, one wave per node (fp8 XW gather) ----------------
__global__ __launch_bounds__(256) void agg_kernel(
    const unsigned char* __restrict__ XW8, const float* __restrict__ s_qk,
    const int* __restrict__ row_off, const int* __restrict__ cidx,
    const float* __restrict__ bias, const __bf16* __restrict__ skipb,
    __bf16* __restrict__ outb, float* __restrict__ outf, float slope, int Nn)
{
    int lane = threadIdx.x & 63;
    int i = blockIdx.x * 4 + (threadIdx.x >> 6);
    if (i >= Nn) return;
    int base = row_off[i];
    int deg = row_off[i + 1] - base;

    int half = lane >> 5;
    int l32 = lane & 31;
    int myh = l32 >> 3;
    int d8 = l32 * 8;

    float acc[8];
    #pragma unroll
    for (int u = 0; u < 8; u++) acc[u] = 0.f;
    float ss0 = 0.f, ss1 = 0.f, ss2 = 0.f, ss3 = 0.f;

    for (int c0 = 0; c0 < deg; c0 += 64) {
        int e = c0 + lane;
        float p0 = 0.f, p1 = 0.f, p2 = 0.f, p3 = 0.f;
        int cc = 0;
        if (e < deg) {
            cc = cidx[base + e];
            int src = cc & 0xFFFFF, et = cc >> 20;
            const float* sq = s_qk + (long)i * 64 + et * 8;
            const float* sk = s_qk + (long)src * 64 + et * 8 + 4;
            float l0 = sq[0] + sk[0]; l0 = l0 < 0.f ? 0.2f * l0 : l0;
            float l1 = sq[1] + sk[1]; l1 = l1 < 0.f ? 0.2f * l1 : l1;
            float l2 = sq[2] + sk[2]; l2 = l2 < 0.f ? 0.2f * l2 : l2;
            float l3 = sq[3] + sk[3]; l3 = l3 < 0.f ? 0.2f * l3 : l3;
            p0 = __expf(fminf(l0, 40.f)); p1 = __expf(fminf(l1, 40.f));
            p2 = __expf(fminf(l2, 40.f)); p3 = __expf(fminf(l3, 40.f));
        }
        ss0 += p0; ss1 += p1; ss2 += p2; ss3 += p3;
        int cnt = min(64, deg - c0);
        for (int j0 = 0; j0 < cnt; j0 += 16) {
            #pragma unroll
            for (int u = 0; u < 8; u++) {
                int srcl = j0 + u * 2 + half;
                float q0 = __shfl(p0, srcl, 64);
                float q1 = __shfl(p1, srcl, 64);
                float q2 = __shfl(p2, srcl, 64);
                float q3 = __shfl(p3, srcl, 64);
                int   cj = __shfl(cc, srcl, 64);
                float w = (myh & 2) ? ((myh & 1) ? q3 : q2) : ((myh & 1) ? q1 : q0);
                int src = cj & 0xFFFFF, et = cj >> 20;
                uint2 xv = *(const uint2*)(XW8 + ((long)et * Nn + src) * 256 + d8);
                v2f f0 = __builtin_amdgcn_cvt_pk_f32_fp8(xv.x, false);
                v2f f1 = __builtin_amdgcn_cvt_pk_f32_fp8(xv.x, true);
                v2f f2 = __builtin_amdgcn_cvt_pk_f32_fp8(xv.y, false);
                v2f f3 = __builtin_amdgcn_cvt_pk_f32_fp8(xv.y, true);
                acc[0] += w * f0.x; acc[1] += w * f0.y;
                acc[2] += w * f1.x; acc[3] += w * f1.y;
                acc[4] += w * f2.x; acc[5] += w * f2.y;
                acc[6] += w * f3.x; acc[7] += w * f3.y;
            }
        }
    }
    #pragma unroll
    for (int u = 0; u < 8; u++) acc[u] += __shfl_xor(acc[u], 32, 64);
    #pragma unroll
    for (int off = 32; off >= 1; off >>= 1) {
        ss0 += __shfl_xor(ss0, off, 64);
        ss1 += __shfl_xor(ss1, off, 64);
        ss2 += __shfl_xor(ss2, off, 64);
        ss3 += __shfl_xor(ss3, off, 64);
    }
    float ssh = (myh & 2) ? ((myh & 1) ? ss3 : ss2) : ((myh & 1) ? ss1 : ss0);
    float inv = 1.f / fmaxf(ssh, 1e-16f);

    float vout[8];
    #pragma unroll
    for (int u = 0; u < 8; u++) {
        float v = acc[u] * inv + bias[d8 + u];
        if (skipb) v += (float)skipb[(long)i * 256 + d8 + u];
        vout[u] = v < 0.f ? slope * v : v;
    }
    if (outb) {
        if (half == 0) {
            __bf16 tmp[8];
            #pragma unroll
            for (int u = 0; u < 8; u++) tmp[u] = (__bf16)vout[u];
            *(uint4*)(outb + (long)i * 256 + d8) = *(const uint4*)tmp;
        }
    } else {
        float4 f4;
        if (half == 0) { f4 = make_float4(vout[0], vout[1], vout[2], vout[3]);
                         *(float4*)(outf + (long)i * 256 + d8) = f4; }
        else           { f4 = make_float4(vout[4], vout[5], vout[6], vout[7]);
                         *(float4*)(outf + (long)i * 256 + d8 + 4) = f4; }
    }
}

extern "C" void kernel_launch(void* const* d_in, const int* in_sizes, int n_in,
                              void* d_out, int out_size, void* d_ws, size_t ws_size,
                              hipStream_t stream)
{
    const float* kg_emb  = (const float*)d_in[0];
    const float* ccle    = (const float*)d_in[1];
    const int*   node_id = (const int*)d_in[2];
    const int*   edge_ix = (const int*)d_in[3];
    const int*   edge_ty = (const int*)d_in[4];
    const float* ccle_w1 = (const float*)d_in[5];
    const float* ccle_b1 = (const float*)d_in[6];
    const float* ccle_w2 = (const float*)d_in[7];
    const float* ccle_b2 = (const float*)d_in[8];
    const float* w1      = (const float*)d_in[9];
    const float* q1      = (const float*)d_in[10];
    const float* k1      = (const float*)d_in[11];
    const float* bias1   = (const float*)d_in[12];
    const float* w2      = (const float*)d_in[13];
    const float* q2      = (const float*)d_in[14];
    const float* k2      = (const float*)d_in[15];
    const float* bias2   = (const float*)d_in[16];
    const float* skip_w1 = (const float*)d_in[17];
    const float* skip_b1 = (const float*)d_in[18];
    const float* skip_w2 = (const float*)d_in[19];
    const float* skip_b2 = (const float*)d_in[20];

    const int Nn = in_sizes[2];
    const int E  = in_sizes[4];
    const int R  = in_sizes[9] / (256 * 256);

    char* p = (char*)d_ws;
    auto alloc = [&](size_t bytes) { char* r = p; p += (bytes + 255) & ~(size_t)255; return r; };
    __bf16* x_in  = (__bf16*)alloc((size_t)Nn * 256 * 2);
    __bf16* x1    = (__bf16*)alloc((size_t)Nn * 256 * 2);
    __bf16* sh    = (__bf16*)alloc((size_t)Nn * 256 * 2);
    __bf16* skipb = (__bf16*)alloc((size_t)Nn * 256 * 2);
    unsigned char* XW8 = (unsigned char*)alloc((size_t)R * Nn * 256);
    float*  s_qk  = (float*)alloc((size_t)Nn * 64 * 4);
    __bf16* wqkT1 = (__bf16*)alloc((size_t)64 * 256 * 2);
    __bf16* wqkT2 = (__bf16*)alloc((size_t)64 * 256 * 2);
    __bf16* w1t   = (__bf16*)alloc((size_t)R * 65536 * 2);
    __bf16* w2t   = (__bf16*)alloc((size_t)R * 65536 * 2);
    __bf16* sw1t  = (__bf16*)alloc((size_t)65536 * 2);
    __bf16* sw2t  = (__bf16*)alloc((size_t)65536 * 2);
    int* deg     = (int*)alloc((size_t)Nn * 4);
    int* row_off = (int*)alloc((size_t)(Nn + 1) * 4);
    int* cursor  = (int*)alloc((size_t)Nn * 4);
    int* cidx    = (int*)alloc((size_t)E * 4);

    const int mb = (Nn + 127) / 128;
    const int eb = (E + 255) / 256;
    const int grp = (mb + 7) / 8;
    const int R2 = 2 * R;
    const int gemm_blocks = 8 * grp * (R2 + 2);   // R-gemm + fused skip member

    (void)hipMemsetAsync(deg, 0, (size_t)Nn * 4, stream);
    build_x_kernel<<<dim3((Nn + 1) / 2), 256, 0, stream>>>(
        kg_emb, ccle, ccle_w1, ccle_b1, ccle_w2, ccle_b2, node_id, x_in, Nn);
    hist_kernel<<<dim3(eb), 256, 0, stream>>>(edge_ix, deg, E);
    scan_kernel<<<dim3(1), 1024, 0, stream>>>(deg, row_off, cursor, Nn);
    scatter_kernel<<<dim3(eb), 256, 0, stream>>>(edge_ix, edge_ty, cursor, cidx, E);
    transpose_all_kernel<<<dim3(4, 4, 2 * R + 2), 256, 0, stream>>>(
        w1, w2, skip_w1, skip_w2, w1t, w2t, sw1t, sw2t, R);
    wqk_build_kernel<<<dim3(2 * R), 256, 0, stream>>>(
        w1, q1, k1, w2, q2, k2, wqkT1, wqkT2, R);

    // layer 1 (+ fused skip stage 1: sh = lrelu(x_in@sw1t + b1))
    gemm_lds_kernel<<<dim3(gemm_blocks), 256, 0, stream>>>(
        x_in, x_in, w1t, 65536L, sw1t, XW8, (long)Nn * 256, sh, skip_b1, 0.01f, Nn, R2, mb);
    sqk_gemm_kernel<<<dim3(mb), 256, 0, stream>>>(x_in, wqkT1, s_qk, Nn);
    agg_kernel<<<dim3((Nn + 3) / 4), 256, 0, stream>>>(
        XW8, s_qk, row_off, cidx, bias1, nullptr, x1, nullptr, 0.01f, Nn);

    // layer 2 (+ fused skip stage 2: skipb = sh@sw2t + b2)
    gemm_lds_kernel<<<dim3(gemm_blocks), 256, 0, stream>>>(
        x1, sh, w2t, 65536L, sw2t, XW8, (long)Nn * 256, skipb, skip_b2, 1.0f, Nn, R2, mb);
    sqk_gemm_kernel<<<dim3(mb), 256, 0, stream>>>(x1, wqkT2, s_qk, Nn);
    agg_kernel<<<dim3((Nn + 3) / 4), 256, 0, stream>>>(
        XW8, s_qk, row_off, cidx, bias2, skipb, nullptr, (float*)d_out, 0.01f, Nn);
}